// Round 3
// baseline (932.030 us; speedup 1.0000x reference)
//
#include <hip/hip_runtime.h>
#include <math.h>

#define BB 8
#define LL 8192
#define DD 64
#define HH 128
#define NN 64
#define NLAYER 3
#define NCHUNK 32
#define LCHUNK 256   // LL / NCHUNK

// workspace sizes in floats
#define SZ_H   ((size_t)BB*LL*HH)            // 8388608
#define SZ_SL  ((size_t)BB*HH*NCHUNK*NN*2)   // 4194304
#define SZ_P   ((size_t)HH*NN*2)             // 16384
#define SZ_WG4 ((size_t)NLAYER*HH*64*4)      // 98304  (paired-col float4 layout)
#define SZ_WO4 ((size_t)32*64*4)             // 8192
#define SZ_WI4 ((size_t)16*128*4)            // 8192

// ---------------- weight repack kernels ----------------
// wpk4[l][h][ct] = {W[h][2ct], W[h][2ct+1], W[h][2ct+128], W[h][2ct+129]}
// Wglu layout: (L, 2H=256, H=128) row-major; element (g,h) at Wglu[l*256*128 + g*128 + h]
__global__ __launch_bounds__(256) void kW1(const float* __restrict__ Wglu,
                                           float4* __restrict__ wpk4) {
  int tid = blockIdx.x*256 + threadIdx.x;        // < 3*128*64 = 24576
  int l   = tid >> 13;
  int rem = tid & 8191;
  int h   = rem >> 6;
  int ct  = rem & 63;
  const float* base = Wglu + (size_t)l*256*128 + h;
  wpk4[tid] = make_float4(base[(2*ct)*128], base[(2*ct+1)*128],
                          base[(2*ct+128)*128], base[(2*ct+129)*128]);
}

// wo4[h4*64 + d] = {Wout[(4h4+j)*64 + d]}_j
__global__ __launch_bounds__(256) void kW2(const float* __restrict__ Wout,
                                           float4* __restrict__ wo4) {
  int tid = blockIdx.x*256 + threadIdx.x;        // < 2048
  int h4 = tid >> 6, d = tid & 63;
  wo4[tid] = make_float4(Wout[(4*h4+0)*DD + d], Wout[(4*h4+1)*DD + d],
                         Wout[(4*h4+2)*DD + d], Wout[(4*h4+3)*DD + d]);
}

// wip4[k4*128 + col] = {Win[(4k4+j)*128 + col]}_j
__global__ __launch_bounds__(256) void kW3(const float* __restrict__ Win,
                                           float4* __restrict__ wip4) {
  int tid = blockIdx.x*256 + threadIdx.x;        // < 2048
  int k4 = tid >> 7, col = tid & 127;
  wip4[tid] = make_float4(Win[(4*k4+0)*HH + col], Win[(4*k4+1)*HH + col],
                          Win[(4*k4+2)*HH + col], Win[(4*k4+3)*HH + col]);
}

// ---------------- input GEMM: h = x @ W_in + b_in ----------------
// block: 32 rows; thread: 2 cols (2ct,2ct+1) x 8 rows; ct=t&63, rg=t>>6
__global__ __launch_bounds__(256) void kIn(const float* __restrict__ x,
      const float4* __restrict__ wip4, const float* __restrict__ bin,
      float* __restrict__ hout) {
  __shared__ float xs[32][DD];
  size_t row0 = (size_t)blockIdx.x * 32;
  int t = threadIdx.x;
  // stage 1: 32x64 floats = 512 float4, 2 per thread
  #pragma unroll
  for (int k = 0; k < 2; k++) {
    int idx = t + k*256;
    int r = idx >> 4, c4 = idx & 15;
    *reinterpret_cast<float4*>(&xs[r][c4*4]) =
        *reinterpret_cast<const float4*>(&x[(row0 + r)*DD + c4*4]);
  }
  __syncthreads();
  int ct = t & 63, rg = t >> 6;
  float acc[8][2];
  float b0 = bin[2*ct], b1 = bin[2*ct+1];
  #pragma unroll
  for (int r = 0; r < 8; r++) { acc[r][0] = b0; acc[r][1] = b1; }
  for (int k4 = 0; k4 < 16; k4++) {
    float4 w0 = wip4[k4*128 + 2*ct];
    float4 w1 = wip4[k4*128 + 2*ct+1];
    #pragma unroll
    for (int r = 0; r < 8; r++) {
      const float4 x4 = *reinterpret_cast<const float4*>(&xs[rg*8 + r][k4*4]);
      acc[r][0] = fmaf(x4.x, w0.x, fmaf(x4.y, w0.y, fmaf(x4.z, w0.z, fmaf(x4.w, w0.w, acc[r][0]))));
      acc[r][1] = fmaf(x4.x, w1.x, fmaf(x4.y, w1.y, fmaf(x4.z, w1.z, fmaf(x4.w, w1.w, acc[r][1]))));
    }
  }
  #pragma unroll
  for (int r = 0; r < 8; r++) {
    float2 v = make_float2(acc[r][0], acc[r][1]);
    *reinterpret_cast<float2*>(&hout[(row0 + rg*8 + r)*HH + 2*ct]) = v;
  }
}

// ---------------- per-layer SSM parameter precompute ----------------
__global__ __launch_bounds__(256) void kP(const float* __restrict__ logdt,
   const float* __restrict__ logA, const float* __restrict__ Aim,
   const float* __restrict__ Cre, const float* __restrict__ Cim, int layer,
   float* __restrict__ wb, float* __restrict__ cb, float* __restrict__ wl) {
  int tid = blockIdx.x*256 + threadIdx.x;        // < HH*NN = 8192
  int n = tid & 63, h = tid >> 6;
  float dt = expf(logdt[layer*HH + h]);
  int idx = (layer*HH + h)*NN + n;
  float ar = -expf(logA[idx]);
  float ai = Aim[idx];
  float dr = dt*ar, di = dt*ai;
  float er = expf(dr);
  float wr_ = er*cosf(di), wi_ = er*sinf(di);     // w = exp(dt*A)
  float mr = wr_ - 1.f, mi = wi_;                 // expm1(dtA)
  float inv = 1.f/(ar*ar + ai*ai);
  float tr = (mr*ar + mi*ai)*inv;                 // expm1(dtA)/A
  float ti = (mi*ar - mr*ai)*inv;
  float c0 = Cre[idx], c1 = Cim[idx];
  cb[2*tid]   = c0*tr - c1*ti;                    // C_eff
  cb[2*tid+1] = c0*ti + c1*tr;
  wb[2*tid]   = wr_;
  wb[2*tid+1] = wi_;
  float pr = wr_, pi = wi_;                       // w^LCHUNK via 8 squarings
  for (int k = 0; k < 8; k++) { float qr = pr*pr - pi*pi; float qi = 2.f*pr*pi; pr = qr; pi = qi; }
  wl[2*tid] = pr; wl[2*tid+1] = pi;
}

// ---------------- kA: chunk-local end states (zero init) ----------------
__global__ __launch_bounds__(256) void kA(const float* __restrict__ hin,
        const float* __restrict__ wbuf, float* __restrict__ Sloc) {
  int wid  = blockIdx.x*4 + (threadIdx.x >> 6);
  int lane = threadIdx.x & 63;
  int c  = wid & (NCHUNK-1);
  int hg = (wid >> 5) & 15;
  int b  = wid >> 9;
  int g = lane >> 3, j = lane & 7;
  int h = hg*8 + g;
  int n0 = j*8;
  float wr[8], wi[8], sr[8], si[8];
  const float* wp = wbuf + ((size_t)h*NN + n0)*2;
  #pragma unroll
  for (int q = 0; q < 8; q++) { wr[q] = wp[2*q]; wi[q] = wp[2*q+1]; sr[q] = 0.f; si[q] = 0.f; }
  const float* up = hin + (size_t)b*LL*HH + h;
  int l0 = c*LCHUNK;
  for (int lb = 0; lb < LCHUNK; lb += 8) {
    float uv[8];
    #pragma unroll
    for (int q = 0; q < 8; q++) uv[q] = up[(size_t)(l0 + lb + q)*HH];
    #pragma unroll
    for (int q = 0; q < 8; q++) {
      float u = uv[q];
      #pragma unroll
      for (int st = 0; st < 8; st++) {
        float nr = fmaf(wr[st], sr[st], fmaf(-wi[st], si[st], u));
        float ni = fmaf(wi[st], sr[st], wr[st]*si[st]);
        sr[st] = nr; si[st] = ni;
      }
    }
  }
  float* Sp = Sloc + ((((size_t)b*HH + h)*NCHUNK + c)*NN + n0)*2;
  #pragma unroll
  for (int q = 0; q < 8; q++) { Sp[2*q] = sr[q]; Sp[2*q+1] = si[q]; }
}

// ---------------- kB: cross-chunk scan ----------------
__global__ __launch_bounds__(256) void kB(float* __restrict__ Sloc,
                                          const float* __restrict__ wl) {
  int tid = blockIdx.x*256 + threadIdx.x;        // < BB*HH*NN = 65536
  int n = tid & 63;
  int h = (tid >> 6) & 127;
  int b = tid >> 13;
  float wlr = wl[((size_t)h*NN + n)*2], wli = wl[((size_t)h*NN + n)*2 + 1];
  float cr = 0.f, ci = 0.f;
  float* base = Sloc + (((size_t)b*HH + h)*NCHUNK)*NN*2 + (size_t)n*2;
  for (int c = 0; c < NCHUNK; c++) {
    float* p = base + (size_t)c*NN*2;
    float tr_ = p[0], ti_ = p[1];
    p[0] = cr; p[1] = ci;
    float nr = fmaf(wlr, cr, fmaf(-wli, ci, tr_));
    float ni = fmaf(wli, cr, fmaf(wlr, ci, ti_));
    cr = nr; ci = ni;
  }
}

// ---------------- kC: full recurrence from s_init ----------------
__global__ __launch_bounds__(256) void kC(const float* __restrict__ hin,
        const float* __restrict__ wbuf, const float* __restrict__ cbuf,
        const float* __restrict__ Sini, float* __restrict__ y) {
  int wid  = blockIdx.x*4 + (threadIdx.x >> 6);
  int lane = threadIdx.x & 63;
  int c  = wid & (NCHUNK-1);
  int hg = (wid >> 5) & 15;
  int b  = wid >> 9;
  int g = lane >> 3, j = lane & 7;
  int h = hg*8 + g;
  int n0 = j*8;
  float wr[8], wi[8], cre[8], cim[8], sr[8], si[8];
  {
    const float* wp = wbuf + ((size_t)h*NN + n0)*2;
    const float* cp = cbuf + ((size_t)h*NN + n0)*2;
    const float* sp = Sini + ((((size_t)b*HH + h)*NCHUNK + c)*NN + n0)*2;
    #pragma unroll
    for (int q = 0; q < 8; q++) {
      wr[q] = wp[2*q]; wi[q] = wp[2*q+1];
      cre[q] = cp[2*q]; cim[q] = cp[2*q+1];
      sr[q] = sp[2*q]; si[q] = sp[2*q+1];
    }
  }
  const float* up = hin + (size_t)b*LL*HH + h;
  float* yp = y + (size_t)b*LL*HH;
  int l0 = c*LCHUNK;
  for (int lb = 0; lb < LCHUNK; lb += 8) {
    float uv[8];
    #pragma unroll
    for (int q = 0; q < 8; q++) uv[q] = up[(size_t)(l0 + lb + q)*HH];
    float ystore = 0.f;
    #pragma unroll
    for (int q = 0; q < 8; q++) {
      float u = uv[q];
      #pragma unroll
      for (int st = 0; st < 8; st++) {
        float nr = fmaf(wr[st], sr[st], fmaf(-wi[st], si[st], u));
        float ni = fmaf(wi[st], sr[st], wr[st]*si[st]);
        sr[st] = nr; si[st] = ni;
      }
      float y0 = 0.f, y1 = 0.f;
      #pragma unroll
      for (int st = 0; st < 8; st += 2) {
        y0 = fmaf(cre[st],   sr[st],   y0); y0 = fmaf(-cim[st],   si[st],   y0);
        y1 = fmaf(cre[st+1], sr[st+1], y1); y1 = fmaf(-cim[st+1], si[st+1], y1);
      }
      float yv = y0 + y1;
      yv += __shfl_xor(yv, 1);
      yv += __shfl_xor(yv, 2);
      yv += __shfl_xor(yv, 4);
      if (j == q) ystore = 2.f*yv;
    }
    yp[(size_t)(l0 + lb + j)*HH + h] = ystore;
  }
}

// ---------------- kD: skip + gelu + GLU + residual + rmsnorm ----------------
// block: 64 rows. thread: ct=t&63 -> cols {2ct,2ct+1,2ct+128,2ct+129}; rg=t>>6 -> 16 rows.
// y may alias hout (y reads finish in stage 1; writes in stage 5; disjoint rows/block).
__global__ __launch_bounds__(256, 4) void kD(const float* __restrict__ y,
     const float* __restrict__ hin, const float* __restrict__ dskip,
     const float4* __restrict__ wpk4, const float* __restrict__ bglu,
     float* __restrict__ hout) {
  __shared__ float yy[64][HH];      // 32 KB: gelu'd ssm output, reused for glu+res
  __shared__ float rnorm[64];
  size_t row0 = (size_t)blockIdx.x * 64;
  int t = threadIdx.x;
  // ---- stage 1: v = y + u*D_skip; yy = gelu(v).  64x128 = 2048 float4, 8/thread
  #pragma unroll
  for (int k = 0; k < 8; k++) {
    int idx = t + k*256;
    int r = idx >> 5, c4 = idx & 31;
    const float4 u4 = *reinterpret_cast<const float4*>(&hin[(row0 + r)*HH + c4*4]);
    const float4 y4 = *reinterpret_cast<const float4*>(&y[(row0 + r)*HH + c4*4]);
    const float4 d4 = *reinterpret_cast<const float4*>(&dskip[c4*4]);
    float v[4] = { fmaf(u4.x, d4.x, y4.x), fmaf(u4.y, d4.y, y4.y),
                   fmaf(u4.z, d4.z, y4.z), fmaf(u4.w, d4.w, y4.w) };
    float o[4];
    #pragma unroll
    for (int q = 0; q < 4; q++) {
      float vv = v[q];
      float arg = 0.7978845608028654f*(vv + 0.044715f*vv*vv*vv);
      arg = fminf(fmaxf(arg, -15.f), 15.f);
      float e = __expf(2.f*arg);
      float th = (e - 1.f)/(e + 1.f);
      o[q] = 0.5f*vv*(1.f + th);
    }
    *reinterpret_cast<float4*>(&yy[r][c4*4]) = make_float4(o[0], o[1], o[2], o[3]);
  }
  __syncthreads();
  // ---- stage 2: GLU matmul. acc[r][0..1]=a cols, acc[r][2..3]=gate cols
  int ct = t & 63, rg = t >> 6;
  float acc[16][4];
  {
    float b0 = bglu[2*ct], b1 = bglu[2*ct+1], b2 = bglu[2*ct+128], b3 = bglu[2*ct+129];
    #pragma unroll
    for (int r = 0; r < 16; r++) { acc[r][0] = b0; acc[r][1] = b1; acc[r][2] = b2; acc[r][3] = b3; }
  }
  for (int h4 = 0; h4 < 32; h4++) {
    float4 w0 = wpk4[(h4*4+0)*64 + ct];
    float4 w1 = wpk4[(h4*4+1)*64 + ct];
    float4 w2 = wpk4[(h4*4+2)*64 + ct];
    float4 w3 = wpk4[(h4*4+3)*64 + ct];
    #pragma unroll
    for (int r = 0; r < 16; r++) {
      const float4 y4 = *reinterpret_cast<const float4*>(&yy[rg*16 + r][h4*4]);
      acc[r][0] = fmaf(y4.x, w0.x, fmaf(y4.y, w1.x, fmaf(y4.z, w2.x, fmaf(y4.w, w3.x, acc[r][0]))));
      acc[r][1] = fmaf(y4.x, w0.y, fmaf(y4.y, w1.y, fmaf(y4.z, w2.y, fmaf(y4.w, w3.y, acc[r][1]))));
      acc[r][2] = fmaf(y4.x, w0.z, fmaf(y4.y, w1.z, fmaf(y4.z, w2.z, fmaf(y4.w, w3.z, acc[r][2]))));
      acc[r][3] = fmaf(y4.x, w0.w, fmaf(y4.y, w1.w, fmaf(y4.z, w2.w, fmaf(y4.w, w3.w, acc[r][3]))));
    }
  }
  __syncthreads();   // all stage-2 yy reads done before stage-3 overwrites
  // ---- stage 3: glu = a*sigmoid(g) + residual -> back into yy
  #pragma unroll
  for (int r = 0; r < 16; r++) {
    size_t grow = row0 + rg*16 + r;
    const float2 res = *reinterpret_cast<const float2*>(&hin[grow*HH + 2*ct]);
    float s0 = 1.f/(1.f + __expf(-acc[r][2]));
    float s1 = 1.f/(1.f + __expf(-acc[r][3]));
    float2 v = make_float2(fmaf(acc[r][0], s0, res.x), fmaf(acc[r][1], s1, res.y));
    *reinterpret_cast<float2*>(&yy[rg*16 + r][2*ct]) = v;
  }
  __syncthreads();
  // ---- stage 4: row 2-norms. flat conflict-free reads + 32-lane shuffle reduce.
  {
    const float* flat = &yy[0][0];
    #pragma unroll
    for (int i = 0; i < 8; i++) {
      int p = t*4 + i*8192/8;            // t*4 + i*1024
      int row = (t >> 5) + i*8;
      const float4 f = *reinterpret_cast<const float4*>(&flat[p]);
      float s = fmaf(f.x, f.x, fmaf(f.y, f.y, fmaf(f.z, f.z, f.w*f.w)));
      s += __shfl_xor(s, 1); s += __shfl_xor(s, 2); s += __shfl_xor(s, 4);
      s += __shfl_xor(s, 8); s += __shfl_xor(s, 16);
      if ((t & 31) == 0) rnorm[row] = s;
    }
  }
  __syncthreads();
  // ---- stage 5: normalize + write
  #pragma unroll
  for (int k = 0; k < 8; k++) {
    int idx = t + k*256;
    int r = idx >> 5, c4 = idx & 31;
    float scale = 11.313708498984761f / fmaxf(sqrtf(rnorm[r]), 1e-12f);
    float4 f = *reinterpret_cast<const float4*>(&yy[r][c4*4]);
    f.x *= scale; f.y *= scale; f.z *= scale; f.w *= scale;
    *reinterpret_cast<float4*>(&hout[(row0 + r)*HH + c4*4]) = f;
  }
}

// ---------------- kE: out = h @ W_out + b_out ----------------
// block: 64 rows. thread: ct=t&31 -> cols {2ct,2ct+1}; rg=t>>5 -> 8 rows.
__global__ __launch_bounds__(256, 4) void kE(const float* __restrict__ hin,
      const float4* __restrict__ wo4, const float* __restrict__ bout,
      float* __restrict__ out) {
  __shared__ float hs[64][HH];
  size_t row0 = (size_t)blockIdx.x * 64;
  int t = threadIdx.x;
  #pragma unroll
  for (int k = 0; k < 8; k++) {
    int idx = t + k*256;
    int r = idx >> 5, c4 = idx & 31;
    *reinterpret_cast<float4*>(&hs[r][c4*4]) =
        *reinterpret_cast<const float4*>(&hin[(row0 + r)*HH + c4*4]);
  }
  __syncthreads();
  int ct = t & 31, rg = t >> 5;
  float acc[8][2];
  float b0 = bout[2*ct], b1 = bout[2*ct+1];
  #pragma unroll
  for (int r = 0; r < 8; r++) { acc[r][0] = b0; acc[r][1] = b1; }
  for (int h4 = 0; h4 < 32; h4++) {
    float4 w0 = wo4[h4*64 + 2*ct];
    float4 w1 = wo4[h4*64 + 2*ct+1];
    #pragma unroll
    for (int r = 0; r < 8; r++) {
      const float4 h4v = *reinterpret_cast<const float4*>(&hs[rg*8 + r][h4*4]);
      acc[r][0] = fmaf(h4v.x, w0.x, fmaf(h4v.y, w0.y, fmaf(h4v.z, w0.z, fmaf(h4v.w, w0.w, acc[r][0]))));
      acc[r][1] = fmaf(h4v.x, w1.x, fmaf(h4v.y, w1.y, fmaf(h4v.z, w1.z, fmaf(h4v.w, w1.w, acc[r][1]))));
    }
  }
  #pragma unroll
  for (int r = 0; r < 8; r++) {
    float2 v = make_float2(acc[r][0], acc[r][1]);
    *reinterpret_cast<float2*>(&out[(row0 + rg*8 + r)*DD + 2*ct]) = v;
  }
}

extern "C" void kernel_launch(void* const* d_in, const int* in_sizes, int n_in,
                              void* d_out, int out_size, void* d_ws, size_t ws_size,
                              hipStream_t stream) {
  const float* x     = (const float*)d_in[0];
  const float* Win   = (const float*)d_in[1];
  const float* bin   = (const float*)d_in[2];
  const float* logdt = (const float*)d_in[3];
  const float* logA  = (const float*)d_in[4];
  const float* Aim   = (const float*)d_in[5];
  const float* Cre   = (const float*)d_in[6];
  const float* Cim   = (const float*)d_in[7];
  const float* Dsk   = (const float*)d_in[8];
  const float* Wglu  = (const float*)d_in[9];
  const float* bglu  = (const float*)d_in[10];
  const float* Wout  = (const float*)d_in[11];
  const float* bout  = (const float*)d_in[12];
  float* out = (float*)d_out;

  float* ws  = (float*)d_ws;
  float* hA  = ws;
  float* hB  = hA + SZ_H;
  float* Sl  = hB + SZ_H;
  float* wb  = Sl + SZ_SL;
  float* cb  = wb + SZ_P;
  float* wl  = cb + SZ_P;
  float* wg4 = wl + SZ_P;
  float* wo4 = wg4 + SZ_WG4;
  float* wi4 = wo4 + SZ_WO4;
  // total ≈ 21.1M floats ≈ 84.6 MB

  hipLaunchKernelGGL(kW1, dim3(96),   dim3(256), 0, stream, Wglu, (float4*)wg4);
  hipLaunchKernelGGL(kW2, dim3(8),    dim3(256), 0, stream, Wout, (float4*)wo4);
  hipLaunchKernelGGL(kW3, dim3(8),    dim3(256), 0, stream, Win,  (float4*)wi4);
  hipLaunchKernelGGL(kIn, dim3(2048), dim3(256), 0, stream, x, (const float4*)wi4, bin, hA);

  float* hc = hA;
  float* hn = hB;
  for (int layer = 0; layer < NLAYER; ++layer) {
    hipLaunchKernelGGL(kP, dim3(32),   dim3(256), 0, stream,
                       logdt, logA, Aim, Cre, Cim, layer, wb, cb, wl);
    hipLaunchKernelGGL(kA, dim3(1024), dim3(256), 0, stream, hc, wb, Sl);
    hipLaunchKernelGGL(kB, dim3(256),  dim3(256), 0, stream, Sl, wl);
    hipLaunchKernelGGL(kC, dim3(1024), dim3(256), 0, stream, hc, wb, cb, Sl, hn);
    hipLaunchKernelGGL(kD, dim3(1024), dim3(256), 0, stream, hn, hc, Dsk + layer*HH,
                       (const float4*)(wg4 + (size_t)layer*HH*64*4),
                       bglu + layer*2*HH, hn);
    float* tmp = hc; hc = hn; hn = tmp;
  }
  hipLaunchKernelGGL(kE, dim3(1024), dim3(256), 0, stream, hc, (const float4*)wo4, bout, out);
}

// Round 4
// 684.327 us; speedup vs baseline: 1.3620x; 1.3620x over previous
//
#include <hip/hip_runtime.h>
#include <math.h>

#define BB 8
#define LL 8192
#define DD 64
#define HH 128
#define NN 64
#define NLAYER 3
#define NCHUNK 32
#define LCHUNK 256   // LL / NCHUNK

// workspace sizes in floats
#define SZ_H   ((size_t)BB*LL*HH)            // 8388608
#define SZ_SL  ((size_t)BB*HH*NCHUNK*NN*2)   // 4194304
#define SZ_P   ((size_t)HH*NN*2)             // 16384
#define SZ_WG4 ((size_t)NLAYER*HH*64*4)      // 98304  (paired-col float4 layout)
#define SZ_WO4 ((size_t)32*64*4)             // 8192
#define SZ_WI4 ((size_t)16*128*4)            // 8192

// ---------------- weight repack kernels ----------------
// wpk4[l][h][ct] = {W[2ct][h], W[2ct+1][h], W[2ct+128][h], W[2ct+129][h]}
__global__ __launch_bounds__(256) void kW1(const float* __restrict__ Wglu,
                                           float4* __restrict__ wpk4) {
  int tid = blockIdx.x*256 + threadIdx.x;        // < 3*128*64 = 24576
  int l   = tid >> 13;
  int rem = tid & 8191;
  int h   = rem >> 6;
  int ct  = rem & 63;
  const float* base = Wglu + (size_t)l*256*128 + h;
  wpk4[tid] = make_float4(base[(2*ct)*128], base[(2*ct+1)*128],
                          base[(2*ct+128)*128], base[(2*ct+129)*128]);
}

// wo4[h4*64 + d] = {Wout[(4h4+j)*64 + d]}_j
__global__ __launch_bounds__(256) void kW2(const float* __restrict__ Wout,
                                           float4* __restrict__ wo4) {
  int tid = blockIdx.x*256 + threadIdx.x;        // < 2048
  int h4 = tid >> 6, d = tid & 63;
  wo4[tid] = make_float4(Wout[(4*h4+0)*DD + d], Wout[(4*h4+1)*DD + d],
                         Wout[(4*h4+2)*DD + d], Wout[(4*h4+3)*DD + d]);
}

// wip4[k4*128 + col] = {Win[(4k4+j)*128 + col]}_j
__global__ __launch_bounds__(256) void kW3(const float* __restrict__ Win,
                                           float4* __restrict__ wip4) {
  int tid = blockIdx.x*256 + threadIdx.x;        // < 2048
  int k4 = tid >> 7, col = tid & 127;
  wip4[tid] = make_float4(Win[(4*k4+0)*HH + col], Win[(4*k4+1)*HH + col],
                          Win[(4*k4+2)*HH + col], Win[(4*k4+3)*HH + col]);
}

// ---------------- input GEMM: h = x @ W_in + b_in ----------------
__global__ __launch_bounds__(256) void kIn(const float* __restrict__ x,
      const float4* __restrict__ wip4, const float* __restrict__ bin,
      float* __restrict__ hout) {
  __shared__ float xs[32][DD];
  size_t row0 = (size_t)blockIdx.x * 32;
  int t = threadIdx.x;
  #pragma unroll
  for (int k = 0; k < 2; k++) {
    int idx = t + k*256;
    int r = idx >> 4, c4 = idx & 15;
    *reinterpret_cast<float4*>(&xs[r][c4*4]) =
        *reinterpret_cast<const float4*>(&x[(row0 + r)*DD + c4*4]);
  }
  __syncthreads();
  int ct = t & 63, rg = t >> 6;
  float acc[8][2];
  float b0 = bin[2*ct], b1 = bin[2*ct+1];
  #pragma unroll
  for (int r = 0; r < 8; r++) { acc[r][0] = b0; acc[r][1] = b1; }
  for (int k4 = 0; k4 < 16; k4++) {
    float4 w0 = wip4[k4*128 + 2*ct];
    float4 w1 = wip4[k4*128 + 2*ct+1];
    #pragma unroll
    for (int r = 0; r < 8; r++) {
      const float4 x4 = *reinterpret_cast<const float4*>(&xs[rg*8 + r][k4*4]);
      acc[r][0] = fmaf(x4.x, w0.x, fmaf(x4.y, w0.y, fmaf(x4.z, w0.z, fmaf(x4.w, w0.w, acc[r][0]))));
      acc[r][1] = fmaf(x4.x, w1.x, fmaf(x4.y, w1.y, fmaf(x4.z, w1.z, fmaf(x4.w, w1.w, acc[r][1]))));
    }
  }
  #pragma unroll
  for (int r = 0; r < 8; r++) {
    float2 v = make_float2(acc[r][0], acc[r][1]);
    *reinterpret_cast<float2*>(&hout[(row0 + rg*8 + r)*HH + 2*ct]) = v;
  }
}

// ---------------- per-layer SSM parameter precompute ----------------
__global__ __launch_bounds__(256) void kP(const float* __restrict__ logdt,
   const float* __restrict__ logA, const float* __restrict__ Aim,
   const float* __restrict__ Cre, const float* __restrict__ Cim, int layer,
   float* __restrict__ wb, float* __restrict__ cb, float* __restrict__ wl) {
  int tid = blockIdx.x*256 + threadIdx.x;        // < HH*NN = 8192
  int n = tid & 63, h = tid >> 6;
  float dt = expf(logdt[layer*HH + h]);
  int idx = (layer*HH + h)*NN + n;
  float ar = -expf(logA[idx]);
  float ai = Aim[idx];
  float dr = dt*ar, di = dt*ai;
  float er = expf(dr);
  float wr_ = er*cosf(di), wi_ = er*sinf(di);     // w = exp(dt*A)
  float mr = wr_ - 1.f, mi = wi_;                 // expm1(dtA)
  float inv = 1.f/(ar*ar + ai*ai);
  float tr = (mr*ar + mi*ai)*inv;                 // expm1(dtA)/A
  float ti = (mi*ar - mr*ai)*inv;
  float c0 = Cre[idx], c1 = Cim[idx];
  cb[2*tid]   = c0*tr - c1*ti;                    // C_eff
  cb[2*tid+1] = c0*ti + c1*tr;
  wb[2*tid]   = wr_;
  wb[2*tid+1] = wi_;
  float pr = wr_, pi = wi_;                       // w^LCHUNK via 8 squarings
  for (int k = 0; k < 8; k++) { float qr = pr*pr - pi*pi; float qi = 2.f*pr*pi; pr = qr; pi = qi; }
  wl[2*tid] = pr; wl[2*tid+1] = pi;
}

// ---------------- kA: chunk-local end states (zero init) ----------------
__global__ __launch_bounds__(256) void kA(const float* __restrict__ hin,
        const float* __restrict__ wbuf, float* __restrict__ Sloc) {
  int wid  = blockIdx.x*4 + (threadIdx.x >> 6);
  int lane = threadIdx.x & 63;
  int c  = wid & (NCHUNK-1);
  int hg = (wid >> 5) & 15;
  int b  = wid >> 9;
  int g = lane >> 3, j = lane & 7;
  int h = hg*8 + g;
  int n0 = j*8;
  float wr[8], wi[8], sr[8], si[8];
  const float* wp = wbuf + ((size_t)h*NN + n0)*2;
  #pragma unroll
  for (int q = 0; q < 8; q++) { wr[q] = wp[2*q]; wi[q] = wp[2*q+1]; sr[q] = 0.f; si[q] = 0.f; }
  const float* up = hin + (size_t)b*LL*HH + h;
  int l0 = c*LCHUNK;
  for (int lb = 0; lb < LCHUNK; lb += 8) {
    float uv[8];
    #pragma unroll
    for (int q = 0; q < 8; q++) uv[q] = up[(size_t)(l0 + lb + q)*HH];
    #pragma unroll
    for (int q = 0; q < 8; q++) {
      float u = uv[q];
      #pragma unroll
      for (int st = 0; st < 8; st++) {
        float nr = fmaf(wr[st], sr[st], fmaf(-wi[st], si[st], u));
        float ni = fmaf(wi[st], sr[st], wr[st]*si[st]);
        sr[st] = nr; si[st] = ni;
      }
    }
  }
  float* Sp = Sloc + ((((size_t)b*HH + h)*NCHUNK + c)*NN + n0)*2;
  #pragma unroll
  for (int q = 0; q < 8; q++) { Sp[2*q] = sr[q]; Sp[2*q+1] = si[q]; }
}

// ---------------- kB: cross-chunk scan ----------------
__global__ __launch_bounds__(256) void kB(float* __restrict__ Sloc,
                                          const float* __restrict__ wl) {
  int tid = blockIdx.x*256 + threadIdx.x;        // < BB*HH*NN = 65536
  int n = tid & 63;
  int h = (tid >> 6) & 127;
  int b = tid >> 13;
  float wlr = wl[((size_t)h*NN + n)*2], wli = wl[((size_t)h*NN + n)*2 + 1];
  float cr = 0.f, ci = 0.f;
  float* base = Sloc + (((size_t)b*HH + h)*NCHUNK)*NN*2 + (size_t)n*2;
  for (int c = 0; c < NCHUNK; c++) {
    float* p = base + (size_t)c*NN*2;
    float tr_ = p[0], ti_ = p[1];
    p[0] = cr; p[1] = ci;
    float nr = fmaf(wlr, cr, fmaf(-wli, ci, tr_));
    float ni = fmaf(wli, cr, fmaf(wlr, ci, ti_));
    cr = nr; ci = ni;
  }
}

// ---------------- kC: full recurrence from s_init ----------------
__global__ __launch_bounds__(256) void kC(const float* __restrict__ hin,
        const float* __restrict__ wbuf, const float* __restrict__ cbuf,
        const float* __restrict__ Sini, float* __restrict__ y) {
  int wid  = blockIdx.x*4 + (threadIdx.x >> 6);
  int lane = threadIdx.x & 63;
  int c  = wid & (NCHUNK-1);
  int hg = (wid >> 5) & 15;
  int b  = wid >> 9;
  int g = lane >> 3, j = lane & 7;
  int h = hg*8 + g;
  int n0 = j*8;
  float wr[8], wi[8], cre[8], cim[8], sr[8], si[8];
  {
    const float* wp = wbuf + ((size_t)h*NN + n0)*2;
    const float* cp = cbuf + ((size_t)h*NN + n0)*2;
    const float* sp = Sini + ((((size_t)b*HH + h)*NCHUNK + c)*NN + n0)*2;
    #pragma unroll
    for (int q = 0; q < 8; q++) {
      wr[q] = wp[2*q]; wi[q] = wp[2*q+1];
      cre[q] = cp[2*q]; cim[q] = cp[2*q+1];
      sr[q] = sp[2*q]; si[q] = sp[2*q+1];
    }
  }
  const float* up = hin + (size_t)b*LL*HH + h;
  float* yp = y + (size_t)b*LL*HH;
  int l0 = c*LCHUNK;
  for (int lb = 0; lb < LCHUNK; lb += 8) {
    float uv[8];
    #pragma unroll
    for (int q = 0; q < 8; q++) uv[q] = up[(size_t)(l0 + lb + q)*HH];
    float ystore = 0.f;
    #pragma unroll
    for (int q = 0; q < 8; q++) {
      float u = uv[q];
      #pragma unroll
      for (int st = 0; st < 8; st++) {
        float nr = fmaf(wr[st], sr[st], fmaf(-wi[st], si[st], u));
        float ni = fmaf(wi[st], sr[st], wr[st]*si[st]);
        sr[st] = nr; si[st] = ni;
      }
      float y0 = 0.f, y1 = 0.f;
      #pragma unroll
      for (int st = 0; st < 8; st += 2) {
        y0 = fmaf(cre[st],   sr[st],   y0); y0 = fmaf(-cim[st],   si[st],   y0);
        y1 = fmaf(cre[st+1], sr[st+1], y1); y1 = fmaf(-cim[st+1], si[st+1], y1);
      }
      float yv = y0 + y1;
      yv += __shfl_xor(yv, 1);
      yv += __shfl_xor(yv, 2);
      yv += __shfl_xor(yv, 4);
      if (j == q) ystore = 2.f*yv;
    }
    yp[(size_t)(l0 + lb + j)*HH + h] = ystore;
  }
}

// ---------------- kD: skip + gelu + GLU + residual + rmsnorm ----------------
// block: 32 rows. thread: ct=t&63 -> cols {2ct,2ct+1,2ct+128,2ct+129}; rg=t>>6 -> 8 rows.
// acc[8][4] = 32 VGPRs to stay spill-free (round-3 acc[16][4] + launch_bounds(,4) spilled:
// VGPR capped at 64, WRITE_SIZE 32->164MB scratch traffic).
// y may alias hout (y reads finish in stage 1; writes in stage 5; disjoint rows/block).
__global__ __launch_bounds__(256) void kD(const float* __restrict__ y,
     const float* __restrict__ hin, const float* __restrict__ dskip,
     const float4* __restrict__ wpk4, const float* __restrict__ bglu,
     float* __restrict__ hout) {
  __shared__ float yy[32][HH];      // 16 KB
  __shared__ float rnorm[32];
  size_t row0 = (size_t)blockIdx.x * 32;
  int t = threadIdx.x;
  // ---- stage 1: v = y + u*D_skip; yy = gelu(v).  32x128 = 1024 float4, 4/thread
  #pragma unroll
  for (int k = 0; k < 4; k++) {
    int idx = t + k*256;
    int r = idx >> 5, c4 = idx & 31;
    const float4 u4 = *reinterpret_cast<const float4*>(&hin[(row0 + r)*HH + c4*4]);
    const float4 y4 = *reinterpret_cast<const float4*>(&y[(row0 + r)*HH + c4*4]);
    const float4 d4 = *reinterpret_cast<const float4*>(&dskip[c4*4]);
    float v[4] = { fmaf(u4.x, d4.x, y4.x), fmaf(u4.y, d4.y, y4.y),
                   fmaf(u4.z, d4.z, y4.z), fmaf(u4.w, d4.w, y4.w) };
    float o[4];
    #pragma unroll
    for (int q = 0; q < 4; q++) {
      float vv = v[q];
      float arg = 0.7978845608028654f*(vv + 0.044715f*vv*vv*vv);
      arg = fminf(fmaxf(arg, -15.f), 15.f);
      float e = __expf(2.f*arg);
      float th = (e - 1.f)/(e + 1.f);
      o[q] = 0.5f*vv*(1.f + th);
    }
    *reinterpret_cast<float4*>(&yy[r][c4*4]) = make_float4(o[0], o[1], o[2], o[3]);
  }
  __syncthreads();
  // ---- stage 2: GLU matmul. acc[r][0..1]=a cols, acc[r][2..3]=gate cols
  int ct = t & 63, rg = t >> 6;
  float acc[8][4];
  {
    float b0 = bglu[2*ct], b1 = bglu[2*ct+1], b2 = bglu[2*ct+128], b3 = bglu[2*ct+129];
    #pragma unroll
    for (int r = 0; r < 8; r++) { acc[r][0] = b0; acc[r][1] = b1; acc[r][2] = b2; acc[r][3] = b3; }
  }
  for (int h4 = 0; h4 < 32; h4++) {
    float4 w0 = wpk4[(h4*4+0)*64 + ct];
    float4 w1 = wpk4[(h4*4+1)*64 + ct];
    float4 w2 = wpk4[(h4*4+2)*64 + ct];
    float4 w3 = wpk4[(h4*4+3)*64 + ct];
    #pragma unroll
    for (int r = 0; r < 8; r++) {
      const float4 y4 = *reinterpret_cast<const float4*>(&yy[rg*8 + r][h4*4]);
      acc[r][0] = fmaf(y4.x, w0.x, fmaf(y4.y, w1.x, fmaf(y4.z, w2.x, fmaf(y4.w, w3.x, acc[r][0]))));
      acc[r][1] = fmaf(y4.x, w0.y, fmaf(y4.y, w1.y, fmaf(y4.z, w2.y, fmaf(y4.w, w3.y, acc[r][1]))));
      acc[r][2] = fmaf(y4.x, w0.z, fmaf(y4.y, w1.z, fmaf(y4.z, w2.z, fmaf(y4.w, w3.z, acc[r][2]))));
      acc[r][3] = fmaf(y4.x, w0.w, fmaf(y4.y, w1.w, fmaf(y4.z, w2.w, fmaf(y4.w, w3.w, acc[r][3]))));
    }
  }
  __syncthreads();   // all stage-2 yy reads done before stage-3 overwrites
  // ---- stage 3: glu = a*sigmoid(g) + residual -> back into yy
  #pragma unroll
  for (int r = 0; r < 8; r++) {
    size_t grow = row0 + rg*8 + r;
    const float2 res = *reinterpret_cast<const float2*>(&hin[grow*HH + 2*ct]);
    float s0 = 1.f/(1.f + __expf(-acc[r][2]));
    float s1 = 1.f/(1.f + __expf(-acc[r][3]));
    float2 v = make_float2(fmaf(acc[r][0], s0, res.x), fmaf(acc[r][1], s1, res.y));
    *reinterpret_cast<float2*>(&yy[rg*8 + r][2*ct]) = v;
  }
  __syncthreads();
  // ---- stage 4: row 2-norms. flat conflict-free reads + 32-lane shuffle reduce.
  {
    const float* flat = &yy[0][0];
    #pragma unroll
    for (int i = 0; i < 4; i++) {
      int idx = i*256 + t;               // 0..1023 float4s
      int row = idx >> 5;
      const float4 f = *reinterpret_cast<const float4*>(&flat[idx*4]);
      float s = fmaf(f.x, f.x, fmaf(f.y, f.y, fmaf(f.z, f.z, f.w*f.w)));
      s += __shfl_xor(s, 1); s += __shfl_xor(s, 2); s += __shfl_xor(s, 4);
      s += __shfl_xor(s, 8); s += __shfl_xor(s, 16);
      if ((t & 31) == 0) rnorm[row] = s;
    }
  }
  __syncthreads();
  // ---- stage 5: normalize + write
  #pragma unroll
  for (int k = 0; k < 4; k++) {
    int idx = t + k*256;
    int r = idx >> 5, c4 = idx & 31;
    float scale = 11.313708498984761f / fmaxf(sqrtf(rnorm[r]), 1e-12f);
    float4 f = *reinterpret_cast<const float4*>(&yy[r][c4*4]);
    f.x *= scale; f.y *= scale; f.z *= scale; f.w *= scale;
    *reinterpret_cast<float4*>(&hout[(row0 + r)*HH + c4*4]) = f;
  }
}

// ---------------- kE: out = h @ W_out + b_out ----------------
__global__ __launch_bounds__(256) void kE(const float* __restrict__ hin,
      const float4* __restrict__ wo4, const float* __restrict__ bout,
      float* __restrict__ out) {
  __shared__ float hs[64][HH];
  size_t row0 = (size_t)blockIdx.x * 64;
  int t = threadIdx.x;
  #pragma unroll
  for (int k = 0; k < 8; k++) {
    int idx = t + k*256;
    int r = idx >> 5, c4 = idx & 31;
    *reinterpret_cast<float4*>(&hs[r][c4*4]) =
        *reinterpret_cast<const float4*>(&hin[(row0 + r)*HH + c4*4]);
  }
  __syncthreads();
  int ct = t & 31, rg = t >> 5;
  float acc[8][2];
  float b0 = bout[2*ct], b1 = bout[2*ct+1];
  #pragma unroll
  for (int r = 0; r < 8; r++) { acc[r][0] = b0; acc[r][1] = b1; }
  for (int h4 = 0; h4 < 32; h4++) {
    float4 w0 = wo4[h4*64 + 2*ct];
    float4 w1 = wo4[h4*64 + 2*ct+1];
    #pragma unroll
    for (int r = 0; r < 8; r++) {
      const float4 h4v = *reinterpret_cast<const float4*>(&hs[rg*8 + r][h4*4]);
      acc[r][0] = fmaf(h4v.x, w0.x, fmaf(h4v.y, w0.y, fmaf(h4v.z, w0.z, fmaf(h4v.w, w0.w, acc[r][0]))));
      acc[r][1] = fmaf(h4v.x, w1.x, fmaf(h4v.y, w1.y, fmaf(h4v.z, w1.z, fmaf(h4v.w, w1.w, acc[r][1]))));
    }
  }
  #pragma unroll
  for (int r = 0; r < 8; r++) {
    float2 v = make_float2(acc[r][0], acc[r][1]);
    *reinterpret_cast<float2*>(&out[(row0 + rg*8 + r)*DD + 2*ct]) = v;
  }
}

extern "C" void kernel_launch(void* const* d_in, const int* in_sizes, int n_in,
                              void* d_out, int out_size, void* d_ws, size_t ws_size,
                              hipStream_t stream) {
  const float* x     = (const float*)d_in[0];
  const float* Win   = (const float*)d_in[1];
  const float* bin   = (const float*)d_in[2];
  const float* logdt = (const float*)d_in[3];
  const float* logA  = (const float*)d_in[4];
  const float* Aim   = (const float*)d_in[5];
  const float* Cre   = (const float*)d_in[6];
  const float* Cim   = (const float*)d_in[7];
  const float* Dsk   = (const float*)d_in[8];
  const float* Wglu  = (const float*)d_in[9];
  const float* bglu  = (const float*)d_in[10];
  const float* Wout  = (const float*)d_in[11];
  const float* bout  = (const float*)d_in[12];
  float* out = (float*)d_out;

  float* ws  = (float*)d_ws;
  float* hA  = ws;
  float* hB  = hA + SZ_H;
  float* Sl  = hB + SZ_H;
  float* wb  = Sl + SZ_SL;
  float* cb  = wb + SZ_P;
  float* wl  = cb + SZ_P;
  float* wg4 = wl + SZ_P;
  float* wo4 = wg4 + SZ_WG4;
  float* wi4 = wo4 + SZ_WO4;
  // total ≈ 21.1M floats ≈ 84.6 MB

  hipLaunchKernelGGL(kW1, dim3(96),   dim3(256), 0, stream, Wglu, (float4*)wg4);
  hipLaunchKernelGGL(kW2, dim3(8),    dim3(256), 0, stream, Wout, (float4*)wo4);
  hipLaunchKernelGGL(kW3, dim3(8),    dim3(256), 0, stream, Win,  (float4*)wi4);
  hipLaunchKernelGGL(kIn, dim3(2048), dim3(256), 0, stream, x, (const float4*)wi4, bin, hA);

  float* hc = hA;
  float* hn = hB;
  for (int layer = 0; layer < NLAYER; ++layer) {
    hipLaunchKernelGGL(kP, dim3(32),   dim3(256), 0, stream,
                       logdt, logA, Aim, Cre, Cim, layer, wb, cb, wl);
    hipLaunchKernelGGL(kA, dim3(1024), dim3(256), 0, stream, hc, wb, Sl);
    hipLaunchKernelGGL(kB, dim3(256),  dim3(256), 0, stream, Sl, wl);
    hipLaunchKernelGGL(kC, dim3(1024), dim3(256), 0, stream, hc, wb, cb, Sl, hn);
    hipLaunchKernelGGL(kD, dim3(2048), dim3(256), 0, stream, hn, hc, Dsk + layer*HH,
                       (const float4*)(wg4 + (size_t)layer*HH*64*4),
                       bglu + layer*2*HH, hn);
    float* tmp = hc; hc = hn; hn = tmp;
  }
  hipLaunchKernelGGL(kE, dim3(1024), dim3(256), 0, stream, hc, (const float4*)wo4, bout, out);
}